// Round 4
// baseline (2775.282 us; speedup 1.0000x reference)
//
#include <hip/hip_runtime.h>
#include <math.h>

#define T_ 256
#define B_ 8
#define S_ 512
#define E_ 1024
#define FF_ 4096
#define V_ 32000
#define LN_EPSF 1e-5f

typedef __attribute__((ext_vector_type(8))) short short8;
typedef __attribute__((ext_vector_type(4))) float f32x4;

// ---------------- block reduction helpers (256 threads = 4 waves) ----------
__device__ __forceinline__ float blkSum(float v, float* sh) {
#pragma unroll
  for (int o = 32; o > 0; o >>= 1) v += __shfl_down(v, o, 64);
  if ((threadIdx.x & 63) == 0) sh[threadIdx.x >> 6] = v;
  __syncthreads();
  float r = sh[0] + sh[1] + sh[2] + sh[3];
  __syncthreads();
  return r;
}
__device__ __forceinline__ float blkMax(float v, float* sh) {
#pragma unroll
  for (int o = 32; o > 0; o >>= 1) v = fmaxf(v, __shfl_down(v, o, 64));
  if ((threadIdx.x & 63) == 0) sh[threadIdx.x >> 6] = v;
  __syncthreads();
  float r = fmaxf(fmaxf(sh[0], sh[1]), fmaxf(sh[2], sh[3]));
  __syncthreads();
  return r;
}
// ---------------- 1024-thread (16 wave) variants ----------------------------
__device__ __forceinline__ float blkSum16(float v, float* sh) {
#pragma unroll
  for (int o = 32; o > 0; o >>= 1) v += __shfl_down(v, o, 64);
  if ((threadIdx.x & 63) == 0) sh[threadIdx.x >> 6] = v;
  __syncthreads();
  float r = 0.f;
#pragma unroll
  for (int i = 0; i < 16; ++i) r += sh[i];
  __syncthreads();
  return r;
}
__device__ __forceinline__ float blkMax16(float v, float* sh) {
#pragma unroll
  for (int o = 32; o > 0; o >>= 1) v = fmaxf(v, __shfl_down(v, o, 64));
  if ((threadIdx.x & 63) == 0) sh[threadIdx.x >> 6] = v;
  __syncthreads();
  float r = -INFINITY;
#pragma unroll
  for (int i = 0; i < 16; ++i) r = fmaxf(r, sh[i]);
  __syncthreads();
  return r;
}

// ---------------- f32 -> bf16 (round to nearest even) -----------------------
__device__ __forceinline__ unsigned short f2bf(float x) {
  unsigned u = __float_as_uint(x);
  u += 0x7FFFu + ((u >> 16) & 1u);
  return (unsigned short)(u >> 16);
}

// bijective XCD swizzle (m204): dispatch slot -> tile id, row-tile fastest
__device__ __forceinline__ void tile_map(int& rowT, int& colT) {
  const unsigned nwg = gridDim.x * gridDim.y;
  const unsigned lin = blockIdx.y * gridDim.x + blockIdx.x;
  const unsigned nq = nwg >> 3, rr = nwg & 7;
  const unsigned xcd = lin & 7, idx = lin >> 3;
  const unsigned swz =
      (xcd < rr ? xcd * (nq + 1) : rr * (nq + 1) + (xcd - rr) * nq) + idx;
  rowT = swz % gridDim.x;   // gridDim.x = row tiles (fastest -> B-panel reuse)
  colT = swz / gridDim.x;
}

// ---------------- bf16 MFMA GEMM: C = (A @ B^T + bias)*scale + sbias[z] -----
// A: M x K fp32 (lda, batch stride aB), B: N x K fp32 (ldb, bB), C (ldc, cB).
// Tiles 128x128, BK=32, 256 thr. grid (rowTiles, colTiles, batch).
__global__ __launch_bounds__(256) void gemm_mfma(
    const float* __restrict__ A, const float* __restrict__ Bm,
    const float* __restrict__ bias, const float* __restrict__ sbias,
    float* __restrict__ C, int K, int lda, int ldb, int ldc,
    long aB, long bB, long cB, float scale, int relu)
{
  __shared__ unsigned short sA[4 * 128 * 8];
  __shared__ unsigned short sB[4 * 128 * 8];
  int rowT, colT;
  tile_map(rowT, colT);
  const int bz = blockIdx.z;
  const int row0 = rowT * 128, col0 = colT * 128;
  const float* Ap = A + (long)bz * aB + (long)row0 * lda;
  const float* Bp = Bm + (long)bz * bB + (long)col0 * ldb;
  float* Cp = C + (long)bz * cB;
  const float sb = sbias ? sbias[bz] : 0.0f;

  const int lane = threadIdx.x & 63, wid = threadIdx.x >> 6;
  const int wr = wid >> 1, wc = wid & 1;     // 2x2 waves, each 64x64
  const int lr = lane & 15, kb = lane >> 4;  // frag row/col, k-block

  const int c0 = threadIdx.x;
  f32x4 acc[4][4];
#pragma unroll
  for (int mi = 0; mi < 4; ++mi)
#pragma unroll
    for (int ni = 0; ni < 4; ++ni) {
      f32x4 z = {0.f, 0.f, 0.f, 0.f};
      acc[mi][ni] = z;
    }

  for (int k0 = 0; k0 < K; k0 += 32) {
#pragma unroll
    for (int i = 0; i < 4; ++i) {
      int c = c0 + (i << 8);                 // 0..1023
      int kq = c & 7, m = c >> 3;            // 8 float4 per row, 128 rows
      const float4 fa = *(const float4*)(Ap + (long)m * lda + k0 + kq * 4);
      unsigned lo = f2bf(fa.x) | ((unsigned)f2bf(fa.y) << 16);
      unsigned hi = f2bf(fa.z) | ((unsigned)f2bf(fa.w) << 16);
      *(uint2*)&sA[((kq >> 1) * 128 + m) * 8 + (kq & 1) * 4] = make_uint2(lo, hi);
      const float4 fb = *(const float4*)(Bp + (long)m * ldb + k0 + kq * 4);
      lo = f2bf(fb.x) | ((unsigned)f2bf(fb.y) << 16);
      hi = f2bf(fb.z) | ((unsigned)f2bf(fb.w) << 16);
      *(uint2*)&sB[((kq >> 1) * 128 + m) * 8 + (kq & 1) * 4] = make_uint2(lo, hi);
    }
    __syncthreads();
    short8 af[4], bfr[4];
#pragma unroll
    for (int mi = 0; mi < 4; ++mi)
      af[mi] = *(const short8*)&sA[(kb * 128 + wr * 64 + mi * 16 + lr) * 8];
#pragma unroll
    for (int ni = 0; ni < 4; ++ni)
      bfr[ni] = *(const short8*)&sB[(kb * 128 + wc * 64 + ni * 16 + lr) * 8];
#pragma unroll
    for (int mi = 0; mi < 4; ++mi)
#pragma unroll
      for (int ni = 0; ni < 4; ++ni)
        acc[mi][ni] = __builtin_amdgcn_mfma_f32_16x16x32_bf16(
            af[mi], bfr[ni], acc[mi][ni], 0, 0, 0);
    __syncthreads();
  }

#pragma unroll
  for (int mi = 0; mi < 4; ++mi)
#pragma unroll
    for (int ni = 0; ni < 4; ++ni) {
      int col = col0 + wc * 64 + ni * 16 + lr;
      float bv = bias ? bias[col] : 0.0f;
#pragma unroll
      for (int r = 0; r < 4; ++r) {
        int row = row0 + wr * 64 + mi * 16 + kb * 4 + r;
        float vv = (acc[mi][ni][r] + bv) * scale + sb;
        if (relu) vv = fmaxf(vv, 0.0f);
        Cp[(long)row * ldc + col] = vv;
      }
    }
}

// ---------------- bf16 MFMA GEMM (B NOT transposed): C = A @ B --------------
// A: M x K fp32 (lda, aB), B: K x N fp32 (ldb = k-row stride, bB), C (ldc, cB)
__global__ __launch_bounds__(256) void gemm_mfma_nt(
    const float* __restrict__ A, const float* __restrict__ Bm,
    float* __restrict__ C, int K, int lda, int ldb, int ldc,
    long aB, long bB, long cB)
{
  __shared__ unsigned short sA[4 * 128 * 8];
  __shared__ unsigned short sB[4 * 128 * 8];
  int rowT, colT;
  tile_map(rowT, colT);
  const int bz = blockIdx.z;
  const int row0 = rowT * 128, col0 = colT * 128;
  const float* Ap = A + (long)bz * aB + (long)row0 * lda;
  const float* Bp = Bm + (long)bz * bB;
  float* Cp = C + (long)bz * cB;

  const int lane = threadIdx.x & 63, wid = threadIdx.x >> 6;
  const int wr = wid >> 1, wc = wid & 1;
  const int lr = lane & 15, kb = lane >> 4;

  const int c0 = threadIdx.x;
  f32x4 acc[4][4];
#pragma unroll
  for (int mi = 0; mi < 4; ++mi)
#pragma unroll
    for (int ni = 0; ni < 4; ++ni) {
      f32x4 z = {0.f, 0.f, 0.f, 0.f};
      acc[mi][ni] = z;
    }

  for (int k0 = 0; k0 < K; k0 += 32) {
#pragma unroll
    for (int i = 0; i < 4; ++i) {
      int c = c0 + (i << 8);                 // 0..1023
      // A tile: same as gemm_mfma
      {
        int kq = c & 7, m = c >> 3;
        const float4 fa = *(const float4*)(Ap + (long)m * lda + k0 + kq * 4);
        unsigned lo = f2bf(fa.x) | ((unsigned)f2bf(fa.y) << 16);
        unsigned hi = f2bf(fa.z) | ((unsigned)f2bf(fa.w) << 16);
        *(uint2*)&sA[((kq >> 1) * 128 + m) * 8 + (kq & 1) * 4] = make_uint2(lo, hi);
      }
      // B tile transposed at staging: kk = c>>5 (0..31), c4 = c&31
      {
        int kk = c >> 5, c4 = c & 31;
        const float4 fb = *(const float4*)(Bp + (long)(k0 + kk) * ldb + col0 + c4 * 4);
        const int kbb = kk >> 3, k8 = kk & 7;
        sB[(kbb * 128 + c4 * 4 + 0) * 8 + k8] = f2bf(fb.x);
        sB[(kbb * 128 + c4 * 4 + 1) * 8 + k8] = f2bf(fb.y);
        sB[(kbb * 128 + c4 * 4 + 2) * 8 + k8] = f2bf(fb.z);
        sB[(kbb * 128 + c4 * 4 + 3) * 8 + k8] = f2bf(fb.w);
      }
    }
    __syncthreads();
    short8 af[4], bfr[4];
#pragma unroll
    for (int mi = 0; mi < 4; ++mi)
      af[mi] = *(const short8*)&sA[(kb * 128 + wr * 64 + mi * 16 + lr) * 8];
#pragma unroll
    for (int ni = 0; ni < 4; ++ni)
      bfr[ni] = *(const short8*)&sB[(kb * 128 + wc * 64 + ni * 16 + lr) * 8];
#pragma unroll
    for (int mi = 0; mi < 4; ++mi)
#pragma unroll
      for (int ni = 0; ni < 4; ++ni)
        acc[mi][ni] = __builtin_amdgcn_mfma_f32_16x16x32_bf16(
            af[mi], bfr[ni], acc[mi][ni], 0, 0, 0);
    __syncthreads();
  }

#pragma unroll
  for (int mi = 0; mi < 4; ++mi)
#pragma unroll
    for (int ni = 0; ni < 4; ++ni) {
      int col = col0 + wc * 64 + ni * 16 + lr;
#pragma unroll
      for (int r = 0; r < 4; ++r) {
        int row = row0 + wr * 64 + mi * 16 + kb * 4 + r;
        Cp[(long)row * ldc + col] = acc[mi][ni][r];
      }
    }
}

// ---------------- masked softmax over s for w[b,t,:] ------------------------
__global__ __launch_bounds__(256) void attn_softmax(
    float* __restrict__ w, const int* __restrict__ mask)
{
  __shared__ float sh[4];
  const int blk = blockIdx.x;          // b*T + t
  const int b = blk / T_;
  float* row = w + (long)blk * S_;
  const int s0 = threadIdx.x, s1 = threadIdx.x + 256;
  const bool k0 = mask[s0 * B_ + b] != 0;
  const bool k1 = mask[s1 * B_ + b] != 0;
  float x0 = k0 ? row[s0] : -INFINITY;
  float x1 = k1 ? row[s1] : -INFINITY;
  float m = blkMax(fmaxf(x0, x1), sh);
  float e0 = k0 ? expf(x0 - m) : 0.0f;
  float e1 = k1 ? expf(x1 - m) : 0.0f;
  float sum = blkSum(e0 + e1, sh);
  float inv = sum > 0.0f ? 1.0f / sum : 0.0f;
  row[s0] = e0 * inv;
  row[s1] = e1 * inv;
}

// ---------------- gates (softmax2 of [outs, LN(attn)] @ div_w^T) + h1 -------
__global__ __launch_bounds__(256) void gates_h1(
    const float* __restrict__ outs, const float* __restrict__ attn,
    const float* __restrict__ aln_g, const float* __restrict__ aln_b,
    const float* __restrict__ div_w, const float* __restrict__ div_b,
    float* __restrict__ h1, float* __restrict__ gen, float* __restrict__ cpy)
{
  __shared__ float sh[4];
  const long base = (long)blockIdx.x * E_;
  float a[4], o[4];
  float sa = 0.f, sa2 = 0.f, shh = 0.f, sh2 = 0.f;
#pragma unroll
  for (int i = 0; i < 4; ++i) {
    int e = threadIdx.x + 256 * i;
    a[i] = attn[base + e];
    o[i] = outs[base + e];
    sa += a[i]; sa2 += a[i] * a[i];
    float t = o[i] + a[i];
    shh += t; sh2 += t * t;
  }
  sa  = blkSum(sa, sh);
  sa2 = blkSum(sa2, sh);
  shh = blkSum(shh, sh);
  sh2 = blkSum(sh2, sh);
  const float ma = sa / E_, va = sa2 / E_ - ma * ma;
  const float mh = shh / E_, vh = sh2 / E_ - mh * mh;
  const float ra = rsqrtf(va + LN_EPSF), rh = rsqrtf(vh + LN_EPSF);

  float z0 = 0.f, z1 = 0.f;
#pragma unroll
  for (int i = 0; i < 4; ++i) {
    int e = threadIdx.x + 256 * i;
    float g = aln_g[e], bb = aln_b[e];
    float an = (a[i] - ma) * ra * g + bb;            // LN(attn)
    float hv = (o[i] + a[i] - mh) * rh * g + bb;     // LN(outs+attn)
    h1[base + e] = hv;
    z0 += o[i] * div_w[e]          + an * div_w[E_ + e];
    z1 += o[i] * div_w[2 * E_ + e] + an * div_w[3 * E_ + e];
  }
  z0 = blkSum(z0, sh);
  z1 = blkSum(z1, sh);
  if (threadIdx.x == 0) {
    z0 += div_b[0]; z1 += div_b[1];
    float mm = fmaxf(z0, z1);
    float e0 = expf(z0 - mm), e1 = expf(z1 - mm);
    float inv = 1.0f / (e0 + e1);
    gen[blockIdx.x] = e0 * inv;
    cpy[blockIdx.x] = e1 * inv;
  }
}

// ---------------- in-place LayerNorm over last dim E ------------------------
__global__ __launch_bounds__(256) void ln_inplace(
    float* __restrict__ x, const float* __restrict__ g, const float* __restrict__ b)
{
  __shared__ float sh[4];
  const long base = (long)blockIdx.x * E_;
  float v[4];
  float s = 0.f, s2 = 0.f;
#pragma unroll
  for (int i = 0; i < 4; ++i) {
    v[i] = x[base + threadIdx.x + 256 * i];
    s += v[i]; s2 += v[i] * v[i];
  }
  s  = blkSum(s, sh);
  s2 = blkSum(s2, sh);
  const float m = s / E_, var = s2 / E_ - m * m;
  const float r = rsqrtf(var + LN_EPSF);
#pragma unroll
  for (int i = 0; i < 4; ++i) {
    int e = threadIdx.x + 256 * i;
    x[base + e] = (v[i] - m) * r * g[e] + b[e];
  }
}

// ---------------- per-row: softmax(V)*gen + scatter(copy) + log, fused ------
// 1024 threads; row cached in 32 regs (single cold read). Scatter atomics are
// block-local (each block owns its row); __threadfence() invalidates L1 so the
// log pass sees the atomic results.
__global__ __launch_bounds__(1024) void final_fused(
    float* __restrict__ out,              // (T*B, V): logits in, log-probs out
    const float* __restrict__ w,          // (B,T,S) post-softmax
    const float* __restrict__ gen, const float* __restrict__ cpy,
    const int* __restrict__ copy_seq)     // (S,B)
{
  __shared__ float sh[16];
  const int r = blockIdx.x;               // t*B + b
  const int t = r / B_, b = r % B_;
  const int tid = threadIdx.x;
  float* row = out + (long)r * V_;

  float vals[32];
  float mx = -INFINITY;
#pragma unroll
  for (int i = 0; i < 32; ++i) {
    int v = tid + (i << 10);
    vals[i] = (v < V_) ? row[v] : -INFINITY;
    mx = fmaxf(mx, vals[i]);
  }
  const float gmx = blkMax16(mx, sh);

  float s = 0.f;
#pragma unroll
  for (int i = 0; i < 32; ++i) {
    int v = tid + (i << 10);
    if (v < V_) { vals[i] = expf(vals[i] - gmx); s += vals[i]; }
  }
  s = blkSum16(s, sh);

  const float scale = gen[r] / s;
#pragma unroll
  for (int i = 0; i < 32; ++i) {
    int v = tid + (i << 10);
    if (v < V_) row[v] = vals[i] * scale;
  }
  __threadfence();
  __syncthreads();

  if (tid < S_) {
    const float cg = cpy[r];
    const float* wrow = w + ((long)b * T_ + t) * S_;
    atomicAdd(&row[copy_seq[tid * B_ + b]], cg * wrow[tid]);
  }
  __threadfence();
  __syncthreads();

#pragma unroll
  for (int i = 0; i < 32; ++i) {
    int v = tid + (i << 10);
    if (v < V_) row[v] = logf(row[v] + 1e-12f);
  }
}

// ---------------- launch ----------------------------------------------------
extern "C" void kernel_launch(void* const* d_in, const int* in_sizes, int n_in,
                              void* d_out, int out_size, void* d_ws, size_t ws_size,
                              hipStream_t stream) {
  (void)in_sizes; (void)n_in; (void)out_size; (void)ws_size;
  const float* outs     = (const float*)d_in[0];
  const float* mem      = (const float*)d_in[1];
  const float* mem_bias = (const float*)d_in[2];
  const float* in_w     = (const float*)d_in[3];
  const float* in_b     = (const float*)d_in[4];
  const float* ow       = (const float*)d_in[5];
  const float* ob       = (const float*)d_in[6];
  const float* aln_g    = (const float*)d_in[7];
  const float* aln_b    = (const float*)d_in[8];
  const float* div_w    = (const float*)d_in[9];
  const float* div_b    = (const float*)d_in[10];
  const float* fc1_w    = (const float*)d_in[11];
  const float* fc1_b    = (const float*)d_in[12];
  const float* fc2_w    = (const float*)d_in[13];
  const float* fc2_b    = (const float*)d_in[14];
  const float* ffn_g    = (const float*)d_in[15];
  const float* ffn_b    = (const float*)d_in[16];
  const float* vocab_w  = (const float*)d_in[17];
  const int*   mask     = (const int*)d_in[18];
  const int*   copy_seq = (const int*)d_in[19];
  float* out = (float*)d_out;
  float* ws  = (float*)d_ws;

  // workspace layout (floats): ctx reuses q, h1 reuses v, h2 reuses k,
  // FFN mid lives in d_out (dead before logits are written)
  float* k    = ws;                   // 4096*1024
  float* v    = ws + 4194304;         // 4096*1024
  float* q    = ws + 8388608;         // 2048*1024
  float* w    = ws + 10485760;        // 8*256*512
  float* attn = ws + 11534336;        // 2048*1024
  float* gen  = ws + 13631488;        // 2048
  float* cpy  = gen + 2048;           // 2048
  float* ctx  = q;
  float* h1   = v;
  float* h2   = k;
  float* mid  = out;

  dim3 blk(256);
  // q = (outs @ Wq^T + bq) * E^-0.5           grid (rowTiles, colTiles)
  gemm_mfma<<<dim3(16, 8), blk, 0, stream>>>(outs, in_w, in_b, nullptr, q,
      1024, 1024, 1024, 1024, 0, 0, 0, 0.03125f, 0);
  // k = mem @ Wk^T + bk
  gemm_mfma<<<dim3(32, 8), blk, 0, stream>>>(mem, in_w + E_ * E_, in_b + E_, nullptr, k,
      1024, 1024, 1024, 1024, 0, 0, 0, 1.0f, 0);
  // v = mem @ Wv^T + bv
  gemm_mfma<<<dim3(32, 8), blk, 0, stream>>>(mem, in_w + 2 * E_ * E_, in_b + 2 * E_, nullptr, v,
      1024, 1024, 1024, 1024, 0, 0, 0, 1.0f, 0);
  // w[b,t,s] = q[t,b,:].k[s,b,:] + mem_bias[b]   (batched, MFMA)
  gemm_mfma<<<dim3(2, 4, 8), blk, 0, stream>>>(q, k, nullptr, mem_bias, w,
      1024, B_ * E_, B_ * E_, S_, E_, E_, (long)T_ * S_, 1.0f, 0);
  attn_softmax<<<dim3(B_ * T_), blk, 0, stream>>>(w, mask);
  // ctx[t,b,:] = sum_s w[b,t,s] * v[s,b,:]   (batched, MFMA, B non-transposed)
  gemm_mfma_nt<<<dim3(2, 8, 8), blk, 0, stream>>>(w, v, ctx,
      512, S_, B_ * E_, B_ * E_, (long)T_ * S_, E_, E_);
  // attn = ctx @ Wo^T + bo
  gemm_mfma<<<dim3(16, 8), blk, 0, stream>>>(ctx, ow, ob, nullptr, attn,
      1024, 1024, 1024, 1024, 0, 0, 0, 1.0f, 0);
  // gates + h1 = LN(outs + attn)
  gates_h1<<<dim3(2048), blk, 0, stream>>>(outs, attn, aln_g, aln_b, div_w, div_b, h1, gen, cpy);
  // mid = relu(h1 @ fc1^T + b1)
  gemm_mfma<<<dim3(16, 32), blk, 0, stream>>>(h1, fc1_w, fc1_b, nullptr, mid,
      1024, 1024, 1024, 4096, 0, 0, 0, 1.0f, 1);
  // h2 = mid @ fc2^T + b2
  gemm_mfma<<<dim3(16, 8), blk, 0, stream>>>(mid, fc2_w, fc2_b, nullptr, h2,
      4096, 4096, 4096, 1024, 0, 0, 0, 1.0f, 0);
  ln_inplace<<<dim3(2048), blk, 0, stream>>>(h2, ffn_g, ffn_b);
  // logits = h2 @ vocab^T  -> d_out  (16 row-tiles fastest => vocab_w read ~once)
  gemm_mfma<<<dim3(16, 250), blk, 0, stream>>>(h2, vocab_w, nullptr, nullptr, out,
      1024, 1024, 1024, 32000, 0, 0, 0, 1.0f, 0);
  // softmax over V * gen, scatter copy probs, log — fused
  final_fused<<<dim3(2048), dim3(1024), 0, stream>>>(out, w, gen, cpy, copy_seq);
}

// Round 5
// 1217.266 us; speedup vs baseline: 2.2799x; 2.2799x over previous
//
#include <hip/hip_runtime.h>
#include <math.h>

#define T_ 256
#define B_ 8
#define S_ 512
#define E_ 1024
#define FF_ 4096
#define V_ 32000
#define LN_EPSF 1e-5f

typedef __attribute__((ext_vector_type(8))) short short8;
typedef __attribute__((ext_vector_type(4))) float f32x4;

// ---------------- block reduction helpers (256 threads = 4 waves) ----------
__device__ __forceinline__ float blkSum(float v, float* sh) {
#pragma unroll
  for (int o = 32; o > 0; o >>= 1) v += __shfl_down(v, o, 64);
  if ((threadIdx.x & 63) == 0) sh[threadIdx.x >> 6] = v;
  __syncthreads();
  float r = sh[0] + sh[1] + sh[2] + sh[3];
  __syncthreads();
  return r;
}
__device__ __forceinline__ float blkMax(float v, float* sh) {
#pragma unroll
  for (int o = 32; o > 0; o >>= 1) v = fmaxf(v, __shfl_down(v, o, 64));
  if ((threadIdx.x & 63) == 0) sh[threadIdx.x >> 6] = v;
  __syncthreads();
  float r = fmaxf(fmaxf(sh[0], sh[1]), fmaxf(sh[2], sh[3]));
  __syncthreads();
  return r;
}
// ---------------- 1024-thread (16 wave) variants ----------------------------
__device__ __forceinline__ float blkSum16(float v, float* sh) {
#pragma unroll
  for (int o = 32; o > 0; o >>= 1) v += __shfl_down(v, o, 64);
  if ((threadIdx.x & 63) == 0) sh[threadIdx.x >> 6] = v;
  __syncthreads();
  float r = 0.f;
#pragma unroll
  for (int i = 0; i < 16; ++i) r += sh[i];
  __syncthreads();
  return r;
}
__device__ __forceinline__ float blkMax16(float v, float* sh) {
#pragma unroll
  for (int o = 32; o > 0; o >>= 1) v = fmaxf(v, __shfl_down(v, o, 64));
  if ((threadIdx.x & 63) == 0) sh[threadIdx.x >> 6] = v;
  __syncthreads();
  float r = -INFINITY;
#pragma unroll
  for (int i = 0; i < 16; ++i) r = fmaxf(r, sh[i]);
  __syncthreads();
  return r;
}

// ---------------- f32 -> bf16 (round to nearest even) -----------------------
__device__ __forceinline__ unsigned short f2bf(float x) {
  unsigned u = __float_as_uint(x);
  u += 0x7FFFu + ((u >> 16) & 1u);
  return (unsigned short)(u >> 16);
}

// bijective XCD swizzle (m204): dispatch slot -> tile id, row-tile fastest
__device__ __forceinline__ void tile_map(int& rowT, int& colT) {
  const unsigned nwg = gridDim.x * gridDim.y;
  const unsigned lin = blockIdx.y * gridDim.x + blockIdx.x;
  const unsigned nq = nwg >> 3, rr = nwg & 7;
  const unsigned xcd = lin & 7, idx = lin >> 3;
  const unsigned swz =
      (xcd < rr ? xcd * (nq + 1) : rr * (nq + 1) + (xcd - rr) * nq) + idx;
  rowT = swz % gridDim.x;   // gridDim.x = row tiles (fastest -> B-panel reuse)
  colT = swz / gridDim.x;
}

// ---------------- bf16 MFMA GEMM: C = (A @ B^T + bias)*scale + sbias[z] -----
// A: M x K fp32 (lda, batch stride aB), B: N x K fp32 (ldb, bB), C (ldc, cB).
// Tiles 128x128, BK=32, 256 thr. grid (rowTiles, colTiles, batch).
__global__ __launch_bounds__(256) void gemm_mfma(
    const float* __restrict__ A, const float* __restrict__ Bm,
    const float* __restrict__ bias, const float* __restrict__ sbias,
    float* __restrict__ C, int K, int lda, int ldb, int ldc,
    long aB, long bB, long cB, float scale, int relu)
{
  __shared__ unsigned short sA[4 * 128 * 8];
  __shared__ unsigned short sB[4 * 128 * 8];
  int rowT, colT;
  tile_map(rowT, colT);
  const int bz = blockIdx.z;
  const int row0 = rowT * 128, col0 = colT * 128;
  const float* Ap = A + (long)bz * aB + (long)row0 * lda;
  const float* Bp = Bm + (long)bz * bB + (long)col0 * ldb;
  float* Cp = C + (long)bz * cB;
  const float sb = sbias ? sbias[bz] : 0.0f;

  const int lane = threadIdx.x & 63, wid = threadIdx.x >> 6;
  const int wr = wid >> 1, wc = wid & 1;     // 2x2 waves, each 64x64
  const int lr = lane & 15, kb = lane >> 4;  // frag row/col, k-block

  const int c0 = threadIdx.x;
  f32x4 acc[4][4];
#pragma unroll
  for (int mi = 0; mi < 4; ++mi)
#pragma unroll
    for (int ni = 0; ni < 4; ++ni) {
      f32x4 z = {0.f, 0.f, 0.f, 0.f};
      acc[mi][ni] = z;
    }

  for (int k0 = 0; k0 < K; k0 += 32) {
#pragma unroll
    for (int i = 0; i < 4; ++i) {
      int c = c0 + (i << 8);                 // 0..1023
      int kq = c & 7, m = c >> 3;            // 8 float4 per row, 128 rows
      const float4 fa = *(const float4*)(Ap + (long)m * lda + k0 + kq * 4);
      unsigned lo = f2bf(fa.x) | ((unsigned)f2bf(fa.y) << 16);
      unsigned hi = f2bf(fa.z) | ((unsigned)f2bf(fa.w) << 16);
      *(uint2*)&sA[((kq >> 1) * 128 + m) * 8 + (kq & 1) * 4] = make_uint2(lo, hi);
      const float4 fb = *(const float4*)(Bp + (long)m * ldb + k0 + kq * 4);
      lo = f2bf(fb.x) | ((unsigned)f2bf(fb.y) << 16);
      hi = f2bf(fb.z) | ((unsigned)f2bf(fb.w) << 16);
      *(uint2*)&sB[((kq >> 1) * 128 + m) * 8 + (kq & 1) * 4] = make_uint2(lo, hi);
    }
    __syncthreads();
    short8 af[4], bfr[4];
#pragma unroll
    for (int mi = 0; mi < 4; ++mi)
      af[mi] = *(const short8*)&sA[(kb * 128 + wr * 64 + mi * 16 + lr) * 8];
#pragma unroll
    for (int ni = 0; ni < 4; ++ni)
      bfr[ni] = *(const short8*)&sB[(kb * 128 + wc * 64 + ni * 16 + lr) * 8];
#pragma unroll
    for (int mi = 0; mi < 4; ++mi)
#pragma unroll
      for (int ni = 0; ni < 4; ++ni)
        acc[mi][ni] = __builtin_amdgcn_mfma_f32_16x16x32_bf16(
            af[mi], bfr[ni], acc[mi][ni], 0, 0, 0);
    __syncthreads();
  }

#pragma unroll
  for (int mi = 0; mi < 4; ++mi)
#pragma unroll
    for (int ni = 0; ni < 4; ++ni) {
      int col = col0 + wc * 64 + ni * 16 + lr;
      float bv = bias ? bias[col] : 0.0f;
#pragma unroll
      for (int r = 0; r < 4; ++r) {
        int row = row0 + wr * 64 + mi * 16 + kb * 4 + r;
        float vv = (acc[mi][ni][r] + bv) * scale + sb;
        if (relu) vv = fmaxf(vv, 0.0f);
        Cp[(long)row * ldc + col] = vv;
      }
    }
}

// ---------------- bf16 MFMA GEMM (B NOT transposed): C = A @ B --------------
// A: M x K fp32 (lda, aB), B: K x N fp32 (ldb = k-row stride, bB), C (ldc, cB)
__global__ __launch_bounds__(256) void gemm_mfma_nt(
    const float* __restrict__ A, const float* __restrict__ Bm,
    float* __restrict__ C, int K, int lda, int ldb, int ldc,
    long aB, long bB, long cB)
{
  __shared__ unsigned short sA[4 * 128 * 8];
  __shared__ unsigned short sB[4 * 128 * 8];
  int rowT, colT;
  tile_map(rowT, colT);
  const int bz = blockIdx.z;
  const int row0 = rowT * 128, col0 = colT * 128;
  const float* Ap = A + (long)bz * aB + (long)row0 * lda;
  const float* Bp = Bm + (long)bz * bB;
  float* Cp = C + (long)bz * cB;

  const int lane = threadIdx.x & 63, wid = threadIdx.x >> 6;
  const int wr = wid >> 1, wc = wid & 1;
  const int lr = lane & 15, kb = lane >> 4;

  const int c0 = threadIdx.x;
  f32x4 acc[4][4];
#pragma unroll
  for (int mi = 0; mi < 4; ++mi)
#pragma unroll
    for (int ni = 0; ni < 4; ++ni) {
      f32x4 z = {0.f, 0.f, 0.f, 0.f};
      acc[mi][ni] = z;
    }

  for (int k0 = 0; k0 < K; k0 += 32) {
#pragma unroll
    for (int i = 0; i < 4; ++i) {
      int c = c0 + (i << 8);                 // 0..1023
      {
        int kq = c & 7, m = c >> 3;
        const float4 fa = *(const float4*)(Ap + (long)m * lda + k0 + kq * 4);
        unsigned lo = f2bf(fa.x) | ((unsigned)f2bf(fa.y) << 16);
        unsigned hi = f2bf(fa.z) | ((unsigned)f2bf(fa.w) << 16);
        *(uint2*)&sA[((kq >> 1) * 128 + m) * 8 + (kq & 1) * 4] = make_uint2(lo, hi);
      }
      {
        int kk = c >> 5, c4 = c & 31;
        const float4 fb = *(const float4*)(Bp + (long)(k0 + kk) * ldb + col0 + c4 * 4);
        const int kbb = kk >> 3, k8 = kk & 7;
        sB[(kbb * 128 + c4 * 4 + 0) * 8 + k8] = f2bf(fb.x);
        sB[(kbb * 128 + c4 * 4 + 1) * 8 + k8] = f2bf(fb.y);
        sB[(kbb * 128 + c4 * 4 + 2) * 8 + k8] = f2bf(fb.z);
        sB[(kbb * 128 + c4 * 4 + 3) * 8 + k8] = f2bf(fb.w);
      }
    }
    __syncthreads();
    short8 af[4], bfr[4];
#pragma unroll
    for (int mi = 0; mi < 4; ++mi)
      af[mi] = *(const short8*)&sA[(kb * 128 + wr * 64 + mi * 16 + lr) * 8];
#pragma unroll
    for (int ni = 0; ni < 4; ++ni)
      bfr[ni] = *(const short8*)&sB[(kb * 128 + wc * 64 + ni * 16 + lr) * 8];
#pragma unroll
    for (int mi = 0; mi < 4; ++mi)
#pragma unroll
      for (int ni = 0; ni < 4; ++ni)
        acc[mi][ni] = __builtin_amdgcn_mfma_f32_16x16x32_bf16(
            af[mi], bfr[ni], acc[mi][ni], 0, 0, 0);
    __syncthreads();
  }

#pragma unroll
  for (int mi = 0; mi < 4; ++mi)
#pragma unroll
    for (int ni = 0; ni < 4; ++ni) {
      int col = col0 + wc * 64 + ni * 16 + lr;
#pragma unroll
      for (int r = 0; r < 4; ++r) {
        int row = row0 + wr * 64 + mi * 16 + kb * 4 + r;
        Cp[(long)row * ldc + col] = acc[mi][ni][r];
      }
    }
}

// ---------------- masked softmax over s for w[b,t,:] ------------------------
__global__ __launch_bounds__(256) void attn_softmax(
    float* __restrict__ w, const int* __restrict__ mask)
{
  __shared__ float sh[4];
  const int blk = blockIdx.x;          // b*T + t
  const int b = blk / T_;
  float* row = w + (long)blk * S_;
  const int s0 = threadIdx.x, s1 = threadIdx.x + 256;
  const bool k0 = mask[s0 * B_ + b] != 0;
  const bool k1 = mask[s1 * B_ + b] != 0;
  float x0 = k0 ? row[s0] : -INFINITY;
  float x1 = k1 ? row[s1] : -INFINITY;
  float m = blkMax(fmaxf(x0, x1), sh);
  float e0 = k0 ? expf(x0 - m) : 0.0f;
  float e1 = k1 ? expf(x1 - m) : 0.0f;
  float sum = blkSum(e0 + e1, sh);
  float inv = sum > 0.0f ? 1.0f / sum : 0.0f;
  row[s0] = e0 * inv;
  row[s1] = e1 * inv;
}

// ---------------- gates (softmax2 of [outs, LN(attn)] @ div_w^T) + h1 -------
__global__ __launch_bounds__(256) void gates_h1(
    const float* __restrict__ outs, const float* __restrict__ attn,
    const float* __restrict__ aln_g, const float* __restrict__ aln_b,
    const float* __restrict__ div_w, const float* __restrict__ div_b,
    float* __restrict__ h1, float* __restrict__ gen, float* __restrict__ cpy)
{
  __shared__ float sh[4];
  const long base = (long)blockIdx.x * E_;
  float a[4], o[4];
  float sa = 0.f, sa2 = 0.f, shh = 0.f, sh2 = 0.f;
#pragma unroll
  for (int i = 0; i < 4; ++i) {
    int e = threadIdx.x + 256 * i;
    a[i] = attn[base + e];
    o[i] = outs[base + e];
    sa += a[i]; sa2 += a[i] * a[i];
    float t = o[i] + a[i];
    shh += t; sh2 += t * t;
  }
  sa  = blkSum(sa, sh);
  sa2 = blkSum(sa2, sh);
  shh = blkSum(shh, sh);
  sh2 = blkSum(sh2, sh);
  const float ma = sa / E_, va = sa2 / E_ - ma * ma;
  const float mh = shh / E_, vh = sh2 / E_ - mh * mh;
  const float ra = rsqrtf(va + LN_EPSF), rh = rsqrtf(vh + LN_EPSF);

  float z0 = 0.f, z1 = 0.f;
#pragma unroll
  for (int i = 0; i < 4; ++i) {
    int e = threadIdx.x + 256 * i;
    float g = aln_g[e], bb = aln_b[e];
    float an = (a[i] - ma) * ra * g + bb;            // LN(attn)
    float hv = (o[i] + a[i] - mh) * rh * g + bb;     // LN(outs+attn)
    h1[base + e] = hv;
    z0 += o[i] * div_w[e]          + an * div_w[E_ + e];
    z1 += o[i] * div_w[2 * E_ + e] + an * div_w[3 * E_ + e];
  }
  z0 = blkSum(z0, sh);
  z1 = blkSum(z1, sh);
  if (threadIdx.x == 0) {
    z0 += div_b[0]; z1 += div_b[1];
    float mm = fmaxf(z0, z1);
    float e0 = expf(z0 - mm), e1 = expf(z1 - mm);
    float inv = 1.0f / (e0 + e1);
    gen[blockIdx.x] = e0 * inv;
    cpy[blockIdx.x] = e1 * inv;
  }
}

// ---------------- in-place LayerNorm over last dim E ------------------------
__global__ __launch_bounds__(256) void ln_inplace(
    float* __restrict__ x, const float* __restrict__ g, const float* __restrict__ b)
{
  __shared__ float sh[4];
  const long base = (long)blockIdx.x * E_;
  float v[4];
  float s = 0.f, s2 = 0.f;
#pragma unroll
  for (int i = 0; i < 4; ++i) {
    v[i] = x[base + threadIdx.x + 256 * i];
    s += v[i]; s2 += v[i] * v[i];
  }
  s  = blkSum(s, sh);
  s2 = blkSum(s2, sh);
  const float m = s / E_, var = s2 / E_ - m * m;
  const float r = rsqrtf(var + LN_EPSF);
#pragma unroll
  for (int i = 0; i < 4; ++i) {
    int e = threadIdx.x + 256 * i;
    x[base + e] = (v[i] - m) * r * g[e] + b[e];
  }
}

// ---------------- per-row softmax(V) * gen -> probs (no fences) -------------
// 1024 threads; row cached in 32 regs (single cold read).
__global__ __launch_bounds__(1024) void vocab_softmax(
    float* __restrict__ out, const float* __restrict__ gen)
{
  __shared__ float sh[16];
  const int r = blockIdx.x;               // t*B + b
  const int tid = threadIdx.x;
  float* row = out + (long)r * V_;

  float vals[32];
  float mx = -INFINITY;
#pragma unroll
  for (int i = 0; i < 32; ++i) {
    int v = tid + (i << 10);
    vals[i] = (v < V_) ? row[v] : -INFINITY;
    mx = fmaxf(mx, vals[i]);
  }
  const float gmx = blkMax16(mx, sh);

  float s = 0.f;
#pragma unroll
  for (int i = 0; i < 32; ++i) {
    int v = tid + (i << 10);
    if (v < V_) { vals[i] = expf(vals[i] - gmx); s += vals[i]; }
  }
  s = blkSum16(s, sh);

  const float scale = gen[r] / s;
#pragma unroll
  for (int i = 0; i < 32; ++i) {
    int v = tid + (i << 10);
    if (v < V_) row[v] = vals[i] * scale;
  }
}

// ---------------- scatter copy probs (own dispatch: no fence needed) --------
// one thread per (row, s): 2048*512 = 4096 blocks x 256 threads
__global__ __launch_bounds__(256) void scatter_k(
    float* __restrict__ out, const float* __restrict__ w,
    const float* __restrict__ cpy, const int* __restrict__ copy_seq)
{
  const int g = blockIdx.x * 256 + threadIdx.x;
  const int r = g >> 9, sdx = g & 511;    // r = t*B + b
  const int t = r >> 3, b = r & 7;
  const float contrib = cpy[r] * w[((long)b * T_ + t) * S_ + sdx];
  atomicAdd(&out[(long)r * V_ + copy_seq[sdx * B_ + b]], contrib);
}

// ---------------- elementwise log(p + 1e-12) --------------------------------
__global__ __launch_bounds__(256) void log_k(float* __restrict__ out, long n)
{
  long i = (long)blockIdx.x * 256 + threadIdx.x;
  long stride = (long)gridDim.x * 256;
  for (; i < n; i += stride) out[i] = logf(out[i] + 1e-12f);
}

// ---------------- launch ----------------------------------------------------
extern "C" void kernel_launch(void* const* d_in, const int* in_sizes, int n_in,
                              void* d_out, int out_size, void* d_ws, size_t ws_size,
                              hipStream_t stream) {
  (void)in_sizes; (void)n_in; (void)out_size; (void)ws_size;
  const float* outs     = (const float*)d_in[0];
  const float* mem      = (const float*)d_in[1];
  const float* mem_bias = (const float*)d_in[2];
  const float* in_w     = (const float*)d_in[3];
  const float* in_b     = (const float*)d_in[4];
  const float* ow       = (const float*)d_in[5];
  const float* ob       = (const float*)d_in[6];
  const float* aln_g    = (const float*)d_in[7];
  const float* aln_b    = (const float*)d_in[8];
  const float* div_w    = (const float*)d_in[9];
  const float* div_b    = (const float*)d_in[10];
  const float* fc1_w    = (const float*)d_in[11];
  const float* fc1_b    = (const float*)d_in[12];
  const float* fc2_w    = (const float*)d_in[13];
  const float* fc2_b    = (const float*)d_in[14];
  const float* ffn_g    = (const float*)d_in[15];
  const float* ffn_b    = (const float*)d_in[16];
  const float* vocab_w  = (const float*)d_in[17];
  const int*   mask     = (const int*)d_in[18];
  const int*   copy_seq = (const int*)d_in[19];
  float* out = (float*)d_out;
  float* ws  = (float*)d_ws;

  // workspace layout (floats): ctx reuses q, h1 reuses v, h2 reuses k,
  // FFN mid lives in d_out (dead before logits are written)
  float* k    = ws;                   // 4096*1024
  float* v    = ws + 4194304;         // 4096*1024
  float* q    = ws + 8388608;         // 2048*1024
  float* w    = ws + 10485760;        // 8*256*512
  float* attn = ws + 11534336;        // 2048*1024
  float* gen  = ws + 13631488;        // 2048
  float* cpy  = gen + 2048;           // 2048
  float* ctx  = q;
  float* h1   = v;
  float* h2   = k;
  float* mid  = out;

  dim3 blk(256);
  // q = (outs @ Wq^T + bq) * E^-0.5           grid (rowTiles, colTiles)
  gemm_mfma<<<dim3(16, 8), blk, 0, stream>>>(outs, in_w, in_b, nullptr, q,
      1024, 1024, 1024, 1024, 0, 0, 0, 0.03125f, 0);
  // k = mem @ Wk^T + bk
  gemm_mfma<<<dim3(32, 8), blk, 0, stream>>>(mem, in_w + E_ * E_, in_b + E_, nullptr, k,
      1024, 1024, 1024, 1024, 0, 0, 0, 1.0f, 0);
  // v = mem @ Wv^T + bv
  gemm_mfma<<<dim3(32, 8), blk, 0, stream>>>(mem, in_w + 2 * E_ * E_, in_b + 2 * E_, nullptr, v,
      1024, 1024, 1024, 1024, 0, 0, 0, 1.0f, 0);
  // w[b,t,s] = q[t,b,:].k[s,b,:] + mem_bias[b]   (batched, MFMA)
  gemm_mfma<<<dim3(2, 4, 8), blk, 0, stream>>>(q, k, nullptr, mem_bias, w,
      1024, B_ * E_, B_ * E_, S_, E_, E_, (long)T_ * S_, 1.0f, 0);
  attn_softmax<<<dim3(B_ * T_), blk, 0, stream>>>(w, mask);
  // ctx[t,b,:] = sum_s w[b,t,s] * v[s,b,:]   (batched, MFMA, B non-transposed)
  gemm_mfma_nt<<<dim3(2, 8, 8), blk, 0, stream>>>(w, v, ctx,
      512, S_, B_ * E_, B_ * E_, (long)T_ * S_, E_, E_);
  // attn = ctx @ Wo^T + bo
  gemm_mfma<<<dim3(16, 8), blk, 0, stream>>>(ctx, ow, ob, nullptr, attn,
      1024, 1024, 1024, 1024, 0, 0, 0, 1.0f, 0);
  // gates + h1 = LN(outs + attn)
  gates_h1<<<dim3(2048), blk, 0, stream>>>(outs, attn, aln_g, aln_b, div_w, div_b, h1, gen, cpy);
  // mid = relu(h1 @ fc1^T + b1)
  gemm_mfma<<<dim3(16, 32), blk, 0, stream>>>(h1, fc1_w, fc1_b, nullptr, mid,
      1024, 1024, 1024, 4096, 0, 0, 0, 1.0f, 1);
  // h2 = mid @ fc2^T + b2
  gemm_mfma<<<dim3(16, 8), blk, 0, stream>>>(mid, fc2_w, fc2_b, nullptr, h2,
      4096, 4096, 4096, 1024, 0, 0, 0, 1.0f, 0);
  ln_inplace<<<dim3(2048), blk, 0, stream>>>(h2, ffn_g, ffn_b);
  // logits = h2 @ vocab^T  -> d_out  (16 row-tiles fastest => vocab_w read ~once)
  gemm_mfma<<<dim3(16, 250), blk, 0, stream>>>(h2, vocab_w, nullptr, nullptr, out,
      1024, 1024, 1024, 32000, 0, 0, 0, 1.0f, 0);
  // final stage, fence-free: softmax*gen -> scatter (own dispatch) -> log
  vocab_softmax<<<dim3(2048), dim3(1024), 0, stream>>>(out, gen);
  scatter_k<<<dim3(4096), blk, 0, stream>>>(out, w, cpy, copy_seq);
  log_k<<<dim3(2048), blk, 0, stream>>>(out, (long)2048 * V_);
}

// Round 6
// 901.344 us; speedup vs baseline: 3.0791x; 1.3505x over previous
//
#include <hip/hip_runtime.h>
#include <math.h>

#define T_ 256
#define B_ 8
#define S_ 512
#define E_ 1024
#define FF_ 4096
#define V_ 32000
#define LN_EPSF 1e-5f

typedef __attribute__((ext_vector_type(8))) short short8;
typedef __attribute__((ext_vector_type(4))) float f32x4;

// ---------------- block reduction helpers -----------------------------------
__device__ __forceinline__ float blkSum(float v, float* sh) {
#pragma unroll
  for (int o = 32; o > 0; o >>= 1) v += __shfl_down(v, o, 64);
  if ((threadIdx.x & 63) == 0) sh[threadIdx.x >> 6] = v;
  __syncthreads();
  float r = sh[0] + sh[1] + sh[2] + sh[3];
  __syncthreads();
  return r;
}
__device__ __forceinline__ float blkMax(float v, float* sh) {
#pragma unroll
  for (int o = 32; o > 0; o >>= 1) v = fmaxf(v, __shfl_down(v, o, 64));
  if ((threadIdx.x & 63) == 0) sh[threadIdx.x >> 6] = v;
  __syncthreads();
  float r = fmaxf(fmaxf(sh[0], sh[1]), fmaxf(sh[2], sh[3]));
  __syncthreads();
  return r;
}
__device__ __forceinline__ float blkSum16(float v, float* sh) {
#pragma unroll
  for (int o = 32; o > 0; o >>= 1) v += __shfl_down(v, o, 64);
  if ((threadIdx.x & 63) == 0) sh[threadIdx.x >> 6] = v;
  __syncthreads();
  float r = 0.f;
#pragma unroll
  for (int i = 0; i < 16; ++i) r += sh[i];
  __syncthreads();
  return r;
}
__device__ __forceinline__ float blkMax16(float v, float* sh) {
#pragma unroll
  for (int o = 32; o > 0; o >>= 1) v = fmaxf(v, __shfl_down(v, o, 64));
  if ((threadIdx.x & 63) == 0) sh[threadIdx.x >> 6] = v;
  __syncthreads();
  float r = -INFINITY;
#pragma unroll
  for (int i = 0; i < 16; ++i) r = fmaxf(r, sh[i]);
  __syncthreads();
  return r;
}

// ---------------- f32 -> bf16 via HW cvt_pk (RNE) ---------------------------
__device__ __forceinline__ unsigned pkbf(float a, float b) {
  unsigned r;
  asm("v_cvt_pk_bf16_f32 %0, %1, %2" : "=v"(r) : "v"(a), "v"(b));
  return r;
}
__device__ __forceinline__ unsigned short bf16o(float a) {
  return (unsigned short)(pkbf(a, a) & 0xffffu);
}

// LDS XOR swizzle: bijective, applied on BOTH store and read (ushort index)
__device__ __forceinline__ int swz(int idx) {
  return idx ^ (((idx >> 10) & 3) << 4);
}

// bijective XCD swizzle (m204): row-tile fastest within each XCD chunk
__device__ __forceinline__ void tile_map(int& rowT, int& colT) {
  const unsigned nwg = gridDim.x * gridDim.y;
  const unsigned lin = blockIdx.y * gridDim.x + blockIdx.x;
  const unsigned nq = nwg >> 3, rr = nwg & 7;
  const unsigned xcd = lin & 7, idx = lin >> 3;
  const unsigned s =
      (xcd < rr ? xcd * (nq + 1) : rr * (nq + 1) + (xcd - rr) * nq) + idx;
  rowT = s % gridDim.x;
  colT = s / gridDim.x;
}

// ---------------- cvt: fp32 -> packed bf16 ----------------------------------
__global__ __launch_bounds__(256) void cvt_bf16(
    const float* __restrict__ in, unsigned short* __restrict__ o, int n4)
{
  int i = blockIdx.x * 256 + threadIdx.x;
  if (i < n4) {
    float4 f = ((const float4*)in)[i];
    ((uint2*)o)[i] = make_uint2(pkbf(f.x, f.y), pkbf(f.z, f.w));
  }
}

// ---------------- bf16 MFMA GEMM: C = act((A @ B^T + bias)*scale + sbias) ---
// A: bf16 M x K (lda elems). B: fp32 (BBF=0, cvt at staging) or bf16 (BBF=1),
// N x K (ldb elems). C: fp32 (CBF=0) or bf16 (CBF=1), ldc elems.
// 128x128 tile, BK=32, 256 thr, reg double-buffered staging, swizzled LDS.
template<int BBF, int CBF>
__global__ __launch_bounds__(256) void gemm_bf(
    const unsigned short* __restrict__ A, const void* __restrict__ Bv,
    const float* __restrict__ bias, const float* __restrict__ sbias,
    void* __restrict__ Cv, int K, int lda, int ldb, int ldc,
    long aB, long bB, long cB, float scale, int relu)
{
  __shared__ unsigned short sA[4096];
  __shared__ unsigned short sB[4096];
  int rowT, colT;
  tile_map(rowT, colT);
  const int bz = blockIdx.z;
  const int row0 = rowT * 128, col0 = colT * 128;
  const unsigned short* Ap = A + (long)bz * aB + (long)row0 * lda;
  const char* Bbase = (const char*)Bv +
      ((long)bz * bB + (long)col0 * ldb) * (BBF ? 2 : 4);
  const float sb = sbias ? sbias[bz] : 0.0f;

  const int lane = threadIdx.x & 63, wid = threadIdx.x >> 6;
  const int wr = wid >> 1, wc = wid & 1;
  const int lr = lane & 15, kb = lane >> 4;
  const int kq = threadIdx.x & 7, m0 = threadIdx.x >> 3;

  f32x4 acc[4][4];
#pragma unroll
  for (int mi = 0; mi < 4; ++mi)
#pragma unroll
    for (int ni = 0; ni < 4; ++ni) {
      f32x4 z = {0.f, 0.f, 0.f, 0.f};
      acc[mi][ni] = z;
    }

  uint2 ra[4], rbh[4];
  float4 rbf[4];
  // prologue loads (k0 = 0)
#pragma unroll
  for (int i = 0; i < 4; ++i) {
    int m = m0 + 32 * i;
    ra[i] = *(const uint2*)(Ap + (long)m * lda + kq * 4);
    if constexpr (BBF)
      rbh[i] = *(const uint2*)((const unsigned short*)Bbase + (long)m * ldb + kq * 4);
    else
      rbf[i] = *(const float4*)((const float*)Bbase + (long)m * ldb + kq * 4);
  }

  for (int k0 = 0;;) {
    // stage (convert if fp32) into swizzled LDS
#pragma unroll
    for (int i = 0; i < 4; ++i) {
      int m = m0 + 32 * i;
      int idx = swz(((kq >> 1) * 128 + m) * 8 + (kq & 1) * 4);
      *(uint2*)&sA[idx] = ra[i];
      if constexpr (BBF)
        *(uint2*)&sB[idx] = rbh[i];
      else
        *(uint2*)&sB[idx] = make_uint2(pkbf(rbf[i].x, rbf[i].y),
                                       pkbf(rbf[i].z, rbf[i].w));
    }
    __syncthreads();
    k0 += 32;
    if (k0 < K) {  // issue next tile's loads early; MFMA hides latency
#pragma unroll
      for (int i = 0; i < 4; ++i) {
        int m = m0 + 32 * i;
        ra[i] = *(const uint2*)(Ap + (long)m * lda + k0 + kq * 4);
        if constexpr (BBF)
          rbh[i] = *(const uint2*)((const unsigned short*)Bbase + (long)m * ldb + k0 + kq * 4);
        else
          rbf[i] = *(const float4*)((const float*)Bbase + (long)m * ldb + k0 + kq * 4);
      }
    }
    short8 af[4], bfr[4];
#pragma unroll
    for (int mi = 0; mi < 4; ++mi)
      af[mi] = *(const short8*)&sA[swz((kb * 128 + wr * 64 + mi * 16 + lr) * 8)];
#pragma unroll
    for (int ni = 0; ni < 4; ++ni)
      bfr[ni] = *(const short8*)&sB[swz((kb * 128 + wc * 64 + ni * 16 + lr) * 8)];
#pragma unroll
    for (int mi = 0; mi < 4; ++mi)
#pragma unroll
      for (int ni = 0; ni < 4; ++ni)
        acc[mi][ni] = __builtin_amdgcn_mfma_f32_16x16x32_bf16(
            af[mi], bfr[ni], acc[mi][ni], 0, 0, 0);
    __syncthreads();
    if (k0 >= K) break;
  }

  // epilogue: C/D layout col=lane&15, row=(lane>>4)*4+reg
  char* Cbase = (char*)Cv + (long)bz * cB * (CBF ? 2 : 4);
#pragma unroll
  for (int mi = 0; mi < 4; ++mi)
#pragma unroll
    for (int ni = 0; ni < 4; ++ni) {
      int col = col0 + wc * 64 + ni * 16 + lr;
      float bv = bias ? bias[col] : 0.0f;
#pragma unroll
      for (int r = 0; r < 4; ++r) {
        int row = row0 + wr * 64 + mi * 16 + kb * 4 + r;
        float vv = (acc[mi][ni][r] + bv) * scale + sb;
        if (relu) vv = fmaxf(vv, 0.0f);
        if constexpr (CBF)
          ((unsigned short*)Cbase)[(long)row * ldc + col] = bf16o(vv);
        else
          ((float*)Cbase)[(long)row * ldc + col] = vv;
      }
    }
}

// ---------------- bf16 MFMA GEMM, B NOT transposed (K-major), all-bf16 ------
// A: bf16 M x K (lda). B: bf16 K x N (ldb = k-row stride). C: bf16 (ldc).
__global__ __launch_bounds__(256) void gemm_nt_bb(
    const unsigned short* __restrict__ A, const unsigned short* __restrict__ Bm,
    unsigned short* __restrict__ C, int K, int lda, int ldb, int ldc,
    long aB, long bB, long cB)
{
  __shared__ unsigned short sA[4096];
  __shared__ unsigned short sB[4096];
  int rowT, colT;
  tile_map(rowT, colT);
  const int bz = blockIdx.z;
  const int row0 = rowT * 128, col0 = colT * 128;
  const unsigned short* Ap = A + (long)bz * aB + (long)row0 * lda;
  const unsigned short* Bp = Bm + (long)bz * bB + col0;

  const int lane = threadIdx.x & 63, wid = threadIdx.x >> 6;
  const int wr = wid >> 1, wc = wid & 1;
  const int lr = lane & 15, kb = lane >> 4;
  const int kq = threadIdx.x & 7, m0 = threadIdx.x >> 3;
  const int k8 = threadIdx.x >> 5, c4 = threadIdx.x & 31;  // B: kbb = i

  f32x4 acc[4][4];
#pragma unroll
  for (int mi = 0; mi < 4; ++mi)
#pragma unroll
    for (int ni = 0; ni < 4; ++ni) {
      f32x4 z = {0.f, 0.f, 0.f, 0.f};
      acc[mi][ni] = z;
    }

  uint2 ra[4], rb[4];
#pragma unroll
  for (int i = 0; i < 4; ++i) {
    int m = m0 + 32 * i;
    ra[i] = *(const uint2*)(Ap + (long)m * lda + kq * 4);
    int kk = k8 + 8 * i;
    rb[i] = *(const uint2*)(Bp + (long)kk * ldb + c4 * 4);
  }

  for (int k0 = 0;;) {
#pragma unroll
    for (int i = 0; i < 4; ++i) {
      int m = m0 + 32 * i;
      int idx = swz(((kq >> 1) * 128 + m) * 8 + (kq & 1) * 4);
      *(uint2*)&sA[idx] = ra[i];
      int b0 = (i * 128 + c4 * 4) * 8 + k8;   // transpose at staging
      sB[swz(b0)]      = (unsigned short)(rb[i].x & 0xffffu);
      sB[swz(b0 + 8)]  = (unsigned short)(rb[i].x >> 16);
      sB[swz(b0 + 16)] = (unsigned short)(rb[i].y & 0xffffu);
      sB[swz(b0 + 24)] = (unsigned short)(rb[i].y >> 16);
    }
    __syncthreads();
    k0 += 32;
    if (k0 < K) {
#pragma unroll
      for (int i = 0; i < 4; ++i) {
        int m = m0 + 32 * i;
        ra[i] = *(const uint2*)(Ap + (long)m * lda + k0 + kq * 4);
        int kk = k8 + 8 * i;
        rb[i] = *(const uint2*)(Bp + (long)(k0 + kk) * ldb + c4 * 4);
      }
    }
    short8 af[4], bfr[4];
#pragma unroll
    for (int mi = 0; mi < 4; ++mi)
      af[mi] = *(const short8*)&sA[swz((kb * 128 + wr * 64 + mi * 16 + lr) * 8)];
#pragma unroll
    for (int ni = 0; ni < 4; ++ni)
      bfr[ni] = *(const short8*)&sB[swz((kb * 128 + wc * 64 + ni * 16 + lr) * 8)];
#pragma unroll
    for (int mi = 0; mi < 4; ++mi)
#pragma unroll
      for (int ni = 0; ni < 4; ++ni)
        acc[mi][ni] = __builtin_amdgcn_mfma_f32_16x16x32_bf16(
            af[mi], bfr[ni], acc[mi][ni], 0, 0, 0);
    __syncthreads();
    if (k0 >= K) break;
  }

  unsigned short* Cp = C + (long)bz * cB;
#pragma unroll
  for (int mi = 0; mi < 4; ++mi)
#pragma unroll
    for (int ni = 0; ni < 4; ++ni) {
      int col = col0 + wc * 64 + ni * 16 + lr;
#pragma unroll
      for (int r = 0; r < 4; ++r) {
        int row = row0 + wr * 64 + mi * 16 + kb * 4 + r;
        Cp[(long)row * ldc + col] = bf16o(acc[mi][ni][r]);
      }
    }
}

// ---------------- masked softmax over s; writes fp32 + bf16 copies ----------
__global__ __launch_bounds__(256) void attn_softmax(
    float* __restrict__ w, unsigned short* __restrict__ wbf,
    const int* __restrict__ mask)
{
  __shared__ float sh[4];
  const int blk = blockIdx.x;          // b*T + t
  const int b = blk / T_;
  float* row = w + (long)blk * S_;
  unsigned short* rowb = wbf + (long)blk * S_;
  const int s0 = threadIdx.x, s1 = threadIdx.x + 256;
  const bool k0 = mask[s0 * B_ + b] != 0;
  const bool k1 = mask[s1 * B_ + b] != 0;
  float x0 = k0 ? row[s0] : -INFINITY;
  float x1 = k1 ? row[s1] : -INFINITY;
  float m = blkMax(fmaxf(x0, x1), sh);
  float e0 = k0 ? expf(x0 - m) : 0.0f;
  float e1 = k1 ? expf(x1 - m) : 0.0f;
  float sum = blkSum(e0 + e1, sh);
  float inv = sum > 0.0f ? 1.0f / sum : 0.0f;
  float p0 = e0 * inv, p1 = e1 * inv;
  row[s0] = p0; row[s1] = p1;
  rowb[s0] = bf16o(p0); rowb[s1] = bf16o(p1);
}

// ---------------- gates + h1 = LN(outs+attn) (bf16 out) ---------------------
__global__ __launch_bounds__(256) void gates_h1(
    const float* __restrict__ outs, const float* __restrict__ attn,
    const float* __restrict__ aln_g, const float* __restrict__ aln_b,
    const float* __restrict__ div_w, const float* __restrict__ div_b,
    unsigned short* __restrict__ h1, float* __restrict__ gen, float* __restrict__ cpy)
{
  __shared__ float sh[4];
  const long base = (long)blockIdx.x * E_;
  float a[4], o[4];
  float sa = 0.f, sa2 = 0.f, shh = 0.f, sh2 = 0.f;
#pragma unroll
  for (int i = 0; i < 4; ++i) {
    int e = threadIdx.x + 256 * i;
    a[i] = attn[base + e];
    o[i] = outs[base + e];
    sa += a[i]; sa2 += a[i] * a[i];
    float t = o[i] + a[i];
    shh += t; sh2 += t * t;
  }
  sa  = blkSum(sa, sh);
  sa2 = blkSum(sa2, sh);
  shh = blkSum(shh, sh);
  sh2 = blkSum(sh2, sh);
  const float ma = sa / E_, va = sa2 / E_ - ma * ma;
  const float mh = shh / E_, vh = sh2 / E_ - mh * mh;
  const float ra = rsqrtf(va + LN_EPSF), rh = rsqrtf(vh + LN_EPSF);

  float z0 = 0.f, z1 = 0.f;
#pragma unroll
  for (int i = 0; i < 4; ++i) {
    int e = threadIdx.x + 256 * i;
    float g = aln_g[e], bb = aln_b[e];
    float an = (a[i] - ma) * ra * g + bb;
    float hv = (o[i] + a[i] - mh) * rh * g + bb;
    h1[base + e] = bf16o(hv);
    z0 += o[i] * div_w[e]          + an * div_w[E_ + e];
    z1 += o[i] * div_w[2 * E_ + e] + an * div_w[3 * E_ + e];
  }
  z0 = blkSum(z0, sh);
  z1 = blkSum(z1, sh);
  if (threadIdx.x == 0) {
    z0 += div_b[0]; z1 += div_b[1];
    float mm = fmaxf(z0, z1);
    float e0 = expf(z0 - mm), e1 = expf(z1 - mm);
    float inv = 1.0f / (e0 + e1);
    gen[blockIdx.x] = e0 * inv;
    cpy[blockIdx.x] = e1 * inv;
  }
}

// ---------------- LayerNorm fp32 in -> bf16 out -----------------------------
__global__ __launch_bounds__(256) void ln_bf16(
    const float* __restrict__ x, const float* __restrict__ g,
    const float* __restrict__ b, unsigned short* __restrict__ o)
{
  __shared__ float sh[4];
  const long base = (long)blockIdx.x * E_;
  float v[4];
  float s = 0.f, s2 = 0.f;
#pragma unroll
  for (int i = 0; i < 4; ++i) {
    v[i] = x[base + threadIdx.x + 256 * i];
    s += v[i]; s2 += v[i] * v[i];
  }
  s  = blkSum(s, sh);
  s2 = blkSum(s2, sh);
  const float m = s / E_, var = s2 / E_ - m * m;
  const float r = rsqrtf(var + LN_EPSF);
#pragma unroll
  for (int i = 0; i < 4; ++i) {
    int e = threadIdx.x + 256 * i;
    o[base + e] = bf16o((v[i] - m) * r * g[e] + b[e]);
  }
}

// ---------------- softmax(V)*gen; log non-scattered entries directly --------
// Entries that scatter_k will touch (bitmap of copy_seq) are left as probs.
__global__ __launch_bounds__(1024) void vocab_softmax(
    float* __restrict__ out, const float* __restrict__ gen,
    const int* __restrict__ copy_seq)
{
  __shared__ float sh[16];
  __shared__ unsigned bits[1000];
  const int r = blockIdx.x, b = r & 7;
  const int tid = threadIdx.x;
  float4* row4 = (float4*)(out + (long)r * V_);

  if (tid < 1000) bits[tid] = 0u;
  __syncthreads();
  if (tid < S_) {
    int idx = copy_seq[tid * B_ + b];
    atomicOr(&bits[idx >> 5], 1u << (idx & 31));
  }

  float4 v4[8];
  float mx = -INFINITY;
#pragma unroll
  for (int i = 0; i < 8; ++i) {
    int f = tid + (i << 10);
    if (f < 8000) {
      v4[i] = row4[f];
      mx = fmaxf(fmaxf(mx, fmaxf(v4[i].x, v4[i].y)), fmaxf(v4[i].z, v4[i].w));
    }
  }
  const float gmx = blkMax16(mx, sh);  // barrier also publishes bits

  float s = 0.f;
#pragma unroll
  for (int i = 0; i < 8; ++i) {
    int f = tid + (i << 10);
    if (f < 8000) {
      v4[i].x = expf(v4[i].x - gmx); v4[i].y = expf(v4[i].y - gmx);
      v4[i].z = expf(v4[i].z - gmx); v4[i].w = expf(v4[i].w - gmx);
      s += v4[i].x + v4[i].y + v4[i].z + v4[i].w;
    }
  }
  s = blkSum16(s, sh);

  const float scale = gen[r] / s;
#pragma unroll
  for (int i = 0; i < 8; ++i) {
    int f = tid + (i << 10);
    if (f < 8000) {
      int v0 = f << 2;
      float4 p;
      p.x = v4[i].x * scale; p.y = v4[i].y * scale;
      p.z = v4[i].z * scale; p.w = v4[i].w * scale;
      p.x = (bits[v0 >> 5] >> (v0 & 31) & 1) ? p.x : logf(p.x + 1e-12f);
      p.y = (bits[(v0+1) >> 5] >> ((v0+1) & 31) & 1) ? p.y : logf(p.y + 1e-12f);
      p.z = (bits[(v0+2) >> 5] >> ((v0+2) & 31) & 1) ? p.z : logf(p.z + 1e-12f);
      p.w = (bits[(v0+3) >> 5] >> ((v0+3) & 31) & 1) ? p.w : logf(p.w + 1e-12f);
      row4[f] = p;
    }
  }
}

// ---------------- scatter copy probs (own dispatch) -------------------------
__global__ __launch_bounds__(256) void scatter_k(
    float* __restrict__ out, const float* __restrict__ w,
    const float* __restrict__ cpy, const int* __restrict__ copy_seq)
{
  const int g = blockIdx.x * 256 + threadIdx.x;
  const int r = g >> 9, sdx = g & 511;
  const int t = r >> 3, b = r & 7;
  const float contrib = cpy[r] * w[((long)b * T_ + t) * S_ + sdx];
  atomicAdd(&out[(long)r * V_ + copy_seq[sdx * B_ + b]], contrib);
}

// ---------------- log only the scattered entries (dedupe via bitmap) --------
__global__ __launch_bounds__(1024) void fixup_log(
    float* __restrict__ out, const int* __restrict__ copy_seq)
{
  __shared__ unsigned bits[1000];
  const int r = blockIdx.x, b = r & 7;
  const int tid = threadIdx.x;
  float* row = out + (long)r * V_;
  if (tid < 1000) bits[tid] = 0u;
  __syncthreads();
  if (tid < S_) {
    int idx = copy_seq[tid * B_ + b];
    atomicOr(&bits[idx >> 5], 1u << (idx & 31));
  }
  __syncthreads();
  if (tid < 1000) {
    unsigned wd = bits[tid];
    while (wd) {
      int j = __ffs(wd) - 1;
      int idx = (tid << 5) + j;
      row[idx] = logf(row[idx] + 1e-12f);
      wd &= wd - 1;
    }
  }
}

// ---------------- launch ----------------------------------------------------
extern "C" void kernel_launch(void* const* d_in, const int* in_sizes, int n_in,
                              void* d_out, int out_size, void* d_ws, size_t ws_size,
                              hipStream_t stream) {
  (void)in_sizes; (void)n_in; (void)out_size; (void)ws_size;
  const float* outs     = (const float*)d_in[0];
  const float* mem      = (const float*)d_in[1];
  const float* mem_bias = (const float*)d_in[2];
  const float* in_w     = (const float*)d_in[3];
  const float* in_b     = (const float*)d_in[4];
  const float* ow       = (const float*)d_in[5];
  const float* ob       = (const float*)d_in[6];
  const float* aln_g    = (const float*)d_in[7];
  const float* aln_b    = (const float*)d_in[8];
  const float* div_w    = (const float*)d_in[9];
  const float* div_b    = (const float*)d_in[10];
  const float* fc1_w    = (const float*)d_in[11];
  const float* fc1_b    = (const float*)d_in[12];
  const float* fc2_w    = (const float*)d_in[13];
  const float* fc2_b    = (const float*)d_in[14];
  const float* ffn_g    = (const float*)d_in[15];
  const float* ffn_b    = (const float*)d_in[16];
  const float* vocab_w  = (const float*)d_in[17];
  const int*   mask     = (const int*)d_in[18];
  const int*   copy_seq = (const int*)d_in[19];
  float* out = (float*)d_out;

  // ws layout: bf16 activations + fp32 w/attn. ~59 MB total.
  unsigned short* k_bf    = (unsigned short*)d_ws;         // 4096*1024
  unsigned short* v_bf    = k_bf + 4194304;                // 4096*1024
  unsigned short* q_bf    = v_bf + 4194304;                // 2048*1024
  float*          w       = (float*)(q_bf + 2097152);      // 8*256*512
  float*          attn    = w + 1048576;                   // 2048*1024 (fp32)
  unsigned short* w_bf    = (unsigned short*)(attn + 2097152); // 1M
  unsigned short* ctx_bf  = w_bf + 1048576;                // 2048*1024
  unsigned short* h1_bf   = ctx_bf + 2097152;              // 2048*1024
  unsigned short* h2_bf   = h1_bf + 2097152;               // 2048*1024
  unsigned short* outs_bf = h2_bf + 2097152;               // 2048*1024
  unsigned short* mem_bf  = outs_bf + 2097152;             // 4096*1024
  float*          gen     = (float*)(mem_bf + 4194304);    // 2048
  float*          cpy     = gen + 2048;                    // 2048
  float*          h2      = attn;                          // reuse after gates
  unsigned short* mid_bf  = (unsigned short*)d_out;        // 2048*4096, dead region

  dim3 blk(256);
  cvt_bf16<<<dim3(2048), blk, 0, stream>>>(outs, outs_bf, 524288);
  cvt_bf16<<<dim3(4096), blk, 0, stream>>>(mem, mem_bf, 1048576);
  // q = (outs @ Wq^T + bq) * E^-0.5  -> bf16
  gemm_bf<0,1><<<dim3(16, 8), blk, 0, stream>>>(outs_bf, in_w, in_b, nullptr, q_bf,
      1024, 1024, 1024, 1024, 0, 0, 0, 0.03125f, 0);
  // k, v  -> bf16
  gemm_bf<0,1><<<dim3(32, 8), blk, 0, stream>>>(mem_bf, in_w + E_ * E_, in_b + E_, nullptr, k_bf,
      1024, 1024, 1024, 1024, 0, 0, 0, 1.0f, 0);
  gemm_bf<0,1><<<dim3(32, 8), blk, 0, stream>>>(mem_bf, in_w + 2 * E_ * E_, in_b + 2 * E_, nullptr, v_bf,
      1024, 1024, 1024, 1024, 0, 0, 0, 1.0f, 0);
  // scores w[b,t,s] = q.k + mem_bias[b]   (A,B bf16; C fp32)
  gemm_bf<1,0><<<dim3(2, 4, 8), blk, 0, stream>>>(q_bf, k_bf, nullptr, mem_bias, w,
      1024, B_ * E_, B_ * E_, S_, E_, E_, (long)T_ * S_, 1.0f, 0);
  attn_softmax<<<dim3(B_ * T_), blk, 0, stream>>>(w, w_bf, mask);
  // ctx = w @ v   (all bf16, B K-major)
  gemm_nt_bb<<<dim3(2, 8, 8), blk, 0, stream>>>(w_bf, v_bf, ctx_bf,
      512, S_, B_ * E_, B_ * E_, (long)T_ * S_, E_, E_);
  // attn = ctx @ Wo^T + bo  (fp32 out for LN stats)
  gemm_bf<0,0><<<dim3(16, 8), blk, 0, stream>>>(ctx_bf, ow, ob, nullptr, attn,
      1024, 1024, 1024, 1024, 0, 0, 0, 1.0f, 0);
  gates_h1<<<dim3(2048), blk, 0, stream>>>(outs, attn, aln_g, aln_b, div_w, div_b,
      h1_bf, gen, cpy);
  // mid = relu(h1 @ fc1^T + b1) -> bf16 in d_out
  gemm_bf<0,1><<<dim3(16, 32), blk, 0, stream>>>(h1_bf, fc1_w, fc1_b, nullptr, mid_bf,
      1024, 1024, 1024, 4096, 0, 0, 0, 1.0f, 1);
  // h2 = mid @ fc2^T + b2 -> fp32 (reuses attn buffer)
  gemm_bf<0,0><<<dim3(16, 8), blk, 0, stream>>>(mid_bf, fc2_w, fc2_b, nullptr, h2,
      4096, 4096, 4096, 1024, 0, 0, 0, 1.0f, 0);
  ln_bf16<<<dim3(2048), blk, 0, stream>>>(h2, ffn_g, ffn_b, h2_bf);
  // logits = h2 @ vocab^T -> d_out
  gemm_bf<0,0><<<dim3(16, 250), blk, 0, stream>>>(h2_bf, vocab_w, nullptr, nullptr, out,
      1024, 1024, 1024, 32000, 0, 0, 0, 1.0f, 0);
  // final: softmax*gen (+log for non-scattered) -> scatter -> log fixup
  vocab_softmax<<<dim3(2048), dim3(1024), 0, stream>>>(out, gen, copy_seq);
  scatter_k<<<dim3(4096), blk, 0, stream>>>(out, w, cpy, copy_seq);
  fixup_log<<<dim3(2048), dim3(1024), 0, stream>>>(out, copy_seq);
}